// Round 12
// baseline (903.504 us; speedup 1.0000x reference)
//
#include <hip/hip_runtime.h>
#include <math.h>

typedef float f2 __attribute__((ext_vector_type(2)));

static constexpr int   B_   = 8;
static constexpr int   N_   = 2048;   // points per set
static constexpr int   TPB  = 1024;   // 16 waves/block
static constexpr int   TILE = 32;     // rows/cols owned per block
static constexpr int   NBLK = 512;    // 2 blocks/CU -> 32 waves/CU (max TLP)
static constexpr int   BN   = B_ * N_;
static constexpr float EPS_ = 1e-9f;
static constexpr float LOG2E = 1.4426950408889634f;

// ws layout (floats):
#define WS_X1    (ws)            // [4*BN] packed xyz1 (x,y,z,|p|^2)
#define WS_X2    (ws + 4*BN)     // [4*BN] packed xyz2
#define WS_SATL  (ws + 8*BN)
#define WS_SATR  (ws + 9*BN)
#define WS_SCAL  (ws + 10*BN)    // raw row scale
#define WS_LSCAL (ws + 11*BN)    // log2(scale)
#define WS_LSATR (ws + 12*BN)    // log2(satr)
#define WS_LWR   (ws + 13*BN)    // log2(wr)
#define WS_WR    (ws + 14*BN)    // raw wr
#define WS_COST  (ws + 15*BN)

__global__ void __launch_bounds__(256)
emd_init(const float* __restrict__ xyz1, const float* __restrict__ xyz2,
         float* __restrict__ ws)
{
    const int idx = blockIdx.x * 256 + threadIdx.x;
    if (idx >= BN) return;
    float x = xyz1[idx*3], y = xyz1[idx*3+1], z = xyz1[idx*3+2];
    reinterpret_cast<float4*>(WS_X1)[idx] =
        make_float4(x, y, z, fmaf(x,x, fmaf(y,y, z*z)));
    x = xyz2[idx*3]; y = xyz2[idx*3+1]; z = xyz2[idx*3+2];
    reinterpret_cast<float4*>(WS_X2)[idx] =
        make_float4(x, y, z, fmaf(x,x, fmaf(y,y, z*z)));
    WS_SATL[idx]  = 1.f;
    WS_SATR[idx]  = 1.f;
    WS_LSATR[idx] = 0.f;
    WS_COST[idx]  = 0.f;
}

// wave-level reduce: sum each of 8 row-partials over the 16 lanes of the
// wave sharing (t&3), then lanes 0..3 write [row][wave] into sc[a*512..].
__device__ __forceinline__ void wave_reduce8(float (&s)[8], float* sc, int a,
                                             int t)
{
#pragma unroll
    for (int j = 0; j < 8; ++j) {
        float v = s[j];
        v += __shfl_xor(v, 4, 64);
        v += __shfl_xor(v, 8, 64);
        v += __shfl_xor(v, 16, 64);
        v += __shfl_xor(v, 32, 64);
        s[j] = v;
    }
    const int lane = t & 63, w = t >> 6;       // 16 waves
    if (lane < 4) {
#pragma unroll
        for (int j = 0; j < 8; ++j)
            sc[a*512 + (lane*8 + j)*16 + w] = s[j];
    }
}

// ---- packed sweeps: l = t>>2, 8 iters, stride 256 ----
__device__ __forceinline__ void sweep01(const float4* pts,
    const f2 (&kx)[4], const f2 (&ky)[4], const f2 (&kz)[4], const f2 (&kc)[4],
    int t, float (&s1)[8])
{
#pragma unroll
    for (int j = 0; j < 8; ++j) s1[j] = 0.f;
    int l = t >> 2;
    float4 p = pts[l];
#pragma unroll 4
    for (int i = 0; i < 8; ++i) {
        const int ln = (l + 256) & (N_ - 1);
        const float4 pn = pts[ln];
        const f2 px = (f2){p.x,p.x}, py = (f2){p.y,p.y}, pz = (f2){p.z,p.z};
        const f2 pw = (f2){p.w,p.w};
#pragma unroll
        for (int jp = 0; jp < 4; ++jp) {
            f2 a = kc[jp] + pw;
            a = kz[jp] * pz + a;
            a = ky[jp] * py + a;
            a = kx[jp] * px + a;
            s1[2*jp]   += __builtin_amdgcn_exp2f(a.x);
            s1[2*jp+1] += __builtin_amdgcn_exp2f(a.y);
        }
        p = pn; l = ln;
    }
}

__device__ __forceinline__ void sweep2(const float4* pts, const float* auxB,
    const f2 (&kx)[4], const f2 (&ky)[4], const f2 (&kz)[4], const f2 (&kc)[4],
    float lvA, float lvB, int t, float (&s1)[8], float (&s2)[8], float (&s3)[8])
{
#pragma unroll
    for (int j = 0; j < 8; ++j) { s1[j] = 0.f; s2[j] = 0.f; s3[j] = 0.f; }
    int l = t >> 2;
    float4 p = pts[l];
    float  ab = auxB[l];
#pragma unroll 2
    for (int i = 0; i < 8; ++i) {
        const int ln = (l + 256) & (N_ - 1);
        const float4 pn = pts[ln];
        const float  abn = auxB[ln];
        const f2 px = (f2){p.x,p.x}, py = (f2){p.y,p.y}, pz = (f2){p.z,p.z};
        const float p2s = fmaf(p.x, p.x, fmaf(p.y, p.y, p.z * p.z));
#pragma unroll
        for (int jp = 0; jp < 4; ++jp) {
            f2 dq = kz[jp] * pz + kc[jp];
            dq = ky[jp] * py + dq;
            dq = kx[jp] * px + dq;                  // |q|^2 - 2 p.q
            const float sq0 = __builtin_amdgcn_sqrtf(fmaxf(dq.x + p2s, 0.f));
            const float sq1 = __builtin_amdgcn_sqrtf(fmaxf(dq.y + p2s, 0.f));
            const float eA0 = __builtin_amdgcn_exp2f(fmaf(lvA, dq.x, p.w));
            const float eA1 = __builtin_amdgcn_exp2f(fmaf(lvA, dq.y, p.w));
            const float eB0 = __builtin_amdgcn_exp2f(fmaf(lvB, dq.x, ab));
            const float eB1 = __builtin_amdgcn_exp2f(fmaf(lvB, dq.y, ab));
            s1[2*jp]   += eA0;            s1[2*jp+1] += eA1;
            s2[2*jp]    = fmaf(eA0, sq0, s2[2*jp]);
            s2[2*jp+1]  = fmaf(eA1, sq1, s2[2*jp+1]);
            s3[2*jp]   += eB0;            s3[2*jp+1] += eB1;
        }
        p = pn; ab = abn; l = ln;
    }
}

__device__ __forceinline__ void sweep3(const float4* pts,
    const f2 (&kx)[4], const f2 (&ky)[4], const f2 (&kz)[4],
    int t, float (&s2)[8])
{
#pragma unroll
    for (int j = 0; j < 8; ++j) s2[j] = 0.f;
    int l = t >> 2;
    float4 p = pts[l];
#pragma unroll 4
    for (int i = 0; i < 8; ++i) {
        const int ln = (l + 256) & (N_ - 1);
        const float4 pn = pts[ln];
#pragma unroll
        for (int jp = 0; jp < 4; ++jp) {
            const float dx0 = p.x - kx[jp].x, dy0 = p.y - ky[jp].x,
                        dz0 = p.z - kz[jp].x;
            const float dx1 = p.x - kx[jp].y, dy1 = p.y - ky[jp].y,
                        dz1 = p.z - kz[jp].y;
            const float d20 = fmaf(dx0,dx0, fmaf(dy0,dy0, dz0*dz0));
            const float d21 = fmaf(dx1,dx1, fmaf(dy1,dy1, dz1*dz1));
            s2[2*jp]   = fmaf(p.w, __builtin_amdgcn_sqrtf(fmaxf(d20,0.f)), s2[2*jp]);
            s2[2*jp+1] = fmaf(p.w, __builtin_amdgcn_sqrtf(fmaxf(d21,0.f)), s2[2*jp+1]);
        }
        p = pn; l = ln;
    }
}

// MODE 0: first row sweep  (stream x2, w = lv*p2 + lsatr(=0))  -> scal/lscal
// MODE 1: col sweep        (stream x1, w = lv*p2 + lscal)      -> satr/wr
// MODE 2: P3(lev)+P1(lev+1) row sweep (w = lvA*p2+lwr, aux = lvB*p2+lsatr)
// MODE 3: final row sweep  (w = raw wr)                        -> cost -> out
template<int MODE>
__global__ void __launch_bounds__(TPB, 8)
emd_pass(float* __restrict__ ws, float* __restrict__ out,
         const float lvA, const float lvB)
{
    __shared__ __align__(16) float4 pts[N_];   // 32 KB
    __shared__ float aux[N_];                  // 8 KB: staged arg / reduce scratch

    const int b    = blockIdx.x & 7;     // batch -> XCD pinning (R10-proven)
    const int tile = blockIdx.x >> 3;
    const int t    = threadIdx.x;
    const int rg   = t & 3;

    const float4* x1v = reinterpret_cast<const float4*>(WS_X1) + b * N_;
    const float4* x2v = reinterpret_cast<const float4*>(WS_X2) + b * N_;
    const float* lscal = WS_LSCAL + b * N_;
    const float* lsatr = WS_LSATR + b * N_;
    const float* lwr   = WS_LWR   + b * N_;
    const float* wrp   = WS_WR    + b * N_;

    // ---- staging ----
    for (int p = t; p < N_; p += TPB) {
        if (MODE == 0) {
            float4 v = x2v[p];
            pts[p] = make_float4(v.x, v.y, v.z, lvB * v.w);
        } else if (MODE == 1) {
            float4 v = x1v[p];
            pts[p] = make_float4(v.x, v.y, v.z, fmaf(lvB, v.w, lscal[p]));
        } else if (MODE == 2) {
            float4 v = x2v[p];
            pts[p] = make_float4(v.x, v.y, v.z, fmaf(lvA, v.w, lwr[p]));
            aux[p] = fmaf(lvB, v.w, lsatr[p]);
        } else {
            float4 v = x2v[p];
            pts[p] = make_float4(v.x, v.y, v.z, wrp[p]);
        }
    }

    // ---- owned coefficients, pair-packed ----
    const float4* ownv = (MODE == 1) ? x2v : x1v;
    const int ob = tile * TILE + rg * 8;
    f2 kx[4], ky[4], kz[4], kc[4];
#pragma unroll
    for (int jp = 0; jp < 4; ++jp) {
        float4 v0 = ownv[ob + 2*jp], v1 = ownv[ob + 2*jp + 1];
        if (MODE == 0 || MODE == 1) {
            const float m2 = -2.f * lvB;
            kx[jp] = (f2){m2*v0.x, m2*v1.x};
            ky[jp] = (f2){m2*v0.y, m2*v1.y};
            kz[jp] = (f2){m2*v0.z, m2*v1.z};
            kc[jp] = (f2){lvB*v0.w, lvB*v1.w};
        } else if (MODE == 2) {
            kx[jp] = (f2){-2.f*v0.x, -2.f*v1.x};
            ky[jp] = (f2){-2.f*v0.y, -2.f*v1.y};
            kz[jp] = (f2){-2.f*v0.z, -2.f*v1.z};
            kc[jp] = (f2){v0.w, v1.w};
        } else {
            kx[jp] = (f2){v0.x, v1.x};
            ky[jp] = (f2){v0.y, v1.y};
            kz[jp] = (f2){v0.z, v1.z};
            kc[jp] = (f2){0.f, 0.f};
        }
    }
    __syncthreads();

    float s1[8], s2[8], s3[8];
    if (MODE == 0 || MODE == 1) sweep01(pts, kx, ky, kz, kc, t, s1);
    else if (MODE == 2) sweep2(pts, aux, kx, ky, kz, kc, lvA, lvB, t, s1, s2, s3);
    else                sweep3(pts, kx, ky, kz, t, s2);

    __syncthreads();   // staged aux dead -> reuse as reduce scratch

    if (MODE == 2) {
        wave_reduce8(s1, aux, 0, t);
        wave_reduce8(s2, aux, 1, t);
        wave_reduce8(s3, aux, 2, t);
    } else if (MODE == 3) {
        wave_reduce8(s2, aux, 0, t);
    } else {
        wave_reduce8(s1, aux, 0, t);
    }
    __syncthreads();

    const int gidx = b * N_ + tile * TILE + t;   // valid for t < 32

    if (t < 32) {
        float rs1 = 0.f, rs2 = 0.f, rs3 = 0.f;
#pragma unroll
        for (int w = 0; w < 16; ++w) rs1 += aux[t*16 + w];
        if (MODE == 2) {
#pragma unroll
            for (int w = 0; w < 16; ++w) rs2 += aux[512 + t*16 + w];
#pragma unroll
            for (int w = 0; w < 16; ++w) rs3 += aux[1024 + t*16 + w];
        }
        if (MODE == 0) {
            const float scv = WS_SATL[gidx] / (rs1 + EPS_);
            WS_SCAL[gidx]  = scv;
            WS_LSCAL[gidx] = __log2f(scv);
        } else if (MODE == 1) {
            const float sr  = WS_SATR[gidx];
            const float w1s = sr * rs1;
            const float rr  = fminf(sr / (w1s + EPS_), 1.f);
            const float wrv = sr * rr;
            const float srn = fmaxf(sr - rr * w1s, 0.f);
            WS_SATR[gidx]  = srn;
            WS_WR[gidx]    = wrv;
            WS_LWR[gidx]   = __log2f(wrv);
            WS_LSATR[gidx] = __log2f(srn);
        } else if (MODE == 2) {
            const float scp = WS_SCAL[gidx];
            const float sln = fmaxf(WS_SATL[gidx] - scp * rs1, 0.f);
            WS_COST[gidx]   = fmaf(scp, rs2, WS_COST[gidx]);
            const float scn = sln / (rs3 + EPS_);
            WS_SATL[gidx]  = sln;
            WS_SCAL[gidx]  = scn;
            WS_LSCAL[gidx] = __log2f(scn);
        } else {
            float v = fmaf(WS_SCAL[gidx], rs1, WS_COST[gidx]);
#pragma unroll
            for (int k = 16; k >= 1; k >>= 1) v += __shfl_xor(v, k, 32);
            if (t == 0) atomicAdd(out + b, v);
        }
    }
}

extern "C" void kernel_launch(void* const* d_in, const int* in_sizes, int n_in,
                              void* d_out, int out_size, void* d_ws, size_t ws_size,
                              hipStream_t stream)
{
    const float* xyz1 = (const float*)d_in[0];
    const float* xyz2 = (const float*)d_in[1];
    float* out = (float*)d_out;
    float* ws  = (float*)d_ws;

    hipMemsetAsync(d_out, 0, B_ * sizeof(float), stream);
    emd_init<<<BN / 256, 256, 0, stream>>>(xyz1, xyz2, ws);

    static const float levels[11] = {
        -65536.f, -16384.f, -4096.f, -1024.f, -256.f,
        -64.f, -16.f, -4.f, -1.f, -0.25f, 0.f};

    emd_pass<0><<<NBLK, TPB, 0, stream>>>(ws, out, 0.f, levels[0] * LOG2E);
    emd_pass<1><<<NBLK, TPB, 0, stream>>>(ws, out, 0.f, levels[0] * LOG2E);
    for (int lev = 1; lev < 11; ++lev) {
        emd_pass<2><<<NBLK, TPB, 0, stream>>>(ws, out, levels[lev-1] * LOG2E,
                                                       levels[lev]   * LOG2E);
        emd_pass<1><<<NBLK, TPB, 0, stream>>>(ws, out, 0.f, levels[lev] * LOG2E);
    }
    emd_pass<3><<<NBLK, TPB, 0, stream>>>(ws, out, 0.f, 0.f);
}

// Round 13
// 566.593 us; speedup vs baseline: 1.5946x; 1.5946x over previous
//
#include <hip/hip_runtime.h>
#include <math.h>

typedef float f2 __attribute__((ext_vector_type(2)));

static constexpr int   B_   = 8;
static constexpr int   N_   = 2048;   // points per set
static constexpr int   TPB  = 512;
static constexpr int   TILE = 8;      // rows/cols owned per block
static constexpr int   NBLK = (B_ * N_) / TILE;   // 2048 blocks -> 4/CU (32 w/CU)
static constexpr int   BN   = B_ * N_;
static constexpr float EPS_ = 1e-9f;
static constexpr float LOG2E = 1.4426950408889634f;

// ws layout (floats):
#define WS_X1    (ws)            // [4*BN] packed xyz1 (x,y,z,|p|^2)
#define WS_X2    (ws + 4*BN)     // [4*BN] packed xyz2
#define WS_SATL  (ws + 8*BN)
#define WS_SATR  (ws + 9*BN)
#define WS_SCAL  (ws + 10*BN)    // raw row scale
#define WS_LSCAL (ws + 11*BN)    // log2(scale)
#define WS_LSATR (ws + 12*BN)    // log2(satr)
#define WS_LWR   (ws + 13*BN)    // log2(wr)
#define WS_WR    (ws + 14*BN)    // raw wr
#define WS_COST  (ws + 15*BN)

__global__ void __launch_bounds__(256)
emd_init(const float* __restrict__ xyz1, const float* __restrict__ xyz2,
         float* __restrict__ ws)
{
    const int idx = blockIdx.x * 256 + threadIdx.x;
    if (idx >= BN) return;
    float x = xyz1[idx*3], y = xyz1[idx*3+1], z = xyz1[idx*3+2];
    reinterpret_cast<float4*>(WS_X1)[idx] =
        make_float4(x, y, z, fmaf(x,x, fmaf(y,y, z*z)));
    x = xyz2[idx*3]; y = xyz2[idx*3+1]; z = xyz2[idx*3+2];
    reinterpret_cast<float4*>(WS_X2)[idx] =
        make_float4(x, y, z, fmaf(x,x, fmaf(y,y, z*z)));
    WS_SATL[idx]  = 1.f;
    WS_SATR[idx]  = 1.f;
    WS_LSATR[idx] = 0.f;
    WS_COST[idx]  = 0.f;
}

// full-wave reduce of 8 row-partials (all threads share the same 8 rows);
// lane 0 of each of the 8 waves writes its 8 sums to sc[a*128 + w*16 + j].
__device__ __forceinline__ void wave_reduce8(float (&s)[8], float* sc, int a,
                                             int t)
{
#pragma unroll
    for (int j = 0; j < 8; ++j) {
        float v = s[j];
        v += __shfl_xor(v, 1, 64);
        v += __shfl_xor(v, 2, 64);
        v += __shfl_xor(v, 4, 64);
        v += __shfl_xor(v, 8, 64);
        v += __shfl_xor(v, 16, 64);
        v += __shfl_xor(v, 32, 64);
        s[j] = v;
    }
    if ((t & 63) == 0) {
        const int w = t >> 6;
#pragma unroll
        for (int j = 0; j < 8; ++j) sc[a*128 + w*16 + j] = s[j];
    }
}

// ---- packed sweeps: l = t, stride TPB, 4 iters, 8 evals each ----
__device__ __forceinline__ void sweep01(const float4* pts,
    const f2 (&kx)[4], const f2 (&ky)[4], const f2 (&kz)[4], const f2 (&kc)[4],
    int t, float (&s1)[8])
{
#pragma unroll
    for (int j = 0; j < 8; ++j) s1[j] = 0.f;
    int l = t;
    float4 p = pts[l];
#pragma unroll 2
    for (int i = 0; i < 4; ++i) {
        const int ln = (l + TPB) & (N_ - 1);
        const float4 pn = pts[ln];
        const f2 px = (f2){p.x,p.x}, py = (f2){p.y,p.y}, pz = (f2){p.z,p.z};
        const f2 pw = (f2){p.w,p.w};
#pragma unroll
        for (int jp = 0; jp < 4; ++jp) {
            f2 a = kc[jp] + pw;
            a = kz[jp] * pz + a;
            a = ky[jp] * py + a;
            a = kx[jp] * px + a;
            s1[2*jp]   += __builtin_amdgcn_exp2f(a.x);
            s1[2*jp+1] += __builtin_amdgcn_exp2f(a.y);
        }
        p = pn; l = ln;
    }
}

__device__ __forceinline__ void sweep2(const float4* pts, const float* auxB,
    const f2 (&kx)[4], const f2 (&ky)[4], const f2 (&kz)[4], const f2 (&kc)[4],
    float lvA, float lvB, int t, float (&s1)[8], float (&s2)[8], float (&s3)[8])
{
#pragma unroll
    for (int j = 0; j < 8; ++j) { s1[j] = 0.f; s2[j] = 0.f; s3[j] = 0.f; }
    int l = t;
    float4 p = pts[l];
    float  ab = auxB[l];
#pragma unroll 2
    for (int i = 0; i < 4; ++i) {
        const int ln = (l + TPB) & (N_ - 1);
        const float4 pn = pts[ln];
        const float  abn = auxB[ln];
        const f2 px = (f2){p.x,p.x}, py = (f2){p.y,p.y}, pz = (f2){p.z,p.z};
        const float p2s = fmaf(p.x, p.x, fmaf(p.y, p.y, p.z * p.z));
#pragma unroll
        for (int jp = 0; jp < 4; ++jp) {
            f2 dq = kz[jp] * pz + kc[jp];
            dq = ky[jp] * py + dq;
            dq = kx[jp] * px + dq;                  // |q|^2 - 2 p.q
            const float sq0 = __builtin_amdgcn_sqrtf(fmaxf(dq.x + p2s, 0.f));
            const float sq1 = __builtin_amdgcn_sqrtf(fmaxf(dq.y + p2s, 0.f));
            const float eA0 = __builtin_amdgcn_exp2f(fmaf(lvA, dq.x, p.w));
            const float eA1 = __builtin_amdgcn_exp2f(fmaf(lvA, dq.y, p.w));
            const float eB0 = __builtin_amdgcn_exp2f(fmaf(lvB, dq.x, ab));
            const float eB1 = __builtin_amdgcn_exp2f(fmaf(lvB, dq.y, ab));
            s1[2*jp]   += eA0;            s1[2*jp+1] += eA1;
            s2[2*jp]    = fmaf(eA0, sq0, s2[2*jp]);
            s2[2*jp+1]  = fmaf(eA1, sq1, s2[2*jp+1]);
            s3[2*jp]   += eB0;            s3[2*jp+1] += eB1;
        }
        p = pn; ab = abn; l = ln;
    }
}

__device__ __forceinline__ void sweep3(const float4* pts,
    const f2 (&kx)[4], const f2 (&ky)[4], const f2 (&kz)[4],
    int t, float (&s2)[8])
{
#pragma unroll
    for (int j = 0; j < 8; ++j) s2[j] = 0.f;
    int l = t;
    float4 p = pts[l];
#pragma unroll 2
    for (int i = 0; i < 4; ++i) {
        const int ln = (l + TPB) & (N_ - 1);
        const float4 pn = pts[ln];
#pragma unroll
        for (int jp = 0; jp < 4; ++jp) {
            const float dx0 = p.x - kx[jp].x, dy0 = p.y - ky[jp].x,
                        dz0 = p.z - kz[jp].x;
            const float dx1 = p.x - kx[jp].y, dy1 = p.y - ky[jp].y,
                        dz1 = p.z - kz[jp].y;
            const float d20 = fmaf(dx0,dx0, fmaf(dy0,dy0, dz0*dz0));
            const float d21 = fmaf(dx1,dx1, fmaf(dy1,dy1, dz1*dz1));
            s2[2*jp]   = fmaf(p.w, __builtin_amdgcn_sqrtf(fmaxf(d20,0.f)), s2[2*jp]);
            s2[2*jp+1] = fmaf(p.w, __builtin_amdgcn_sqrtf(fmaxf(d21,0.f)), s2[2*jp+1]);
        }
        p = pn; l = ln;
    }
}

// MODE 0: first row sweep  (stream x2, w = lv*p2 + lsatr(=0))  -> scal/lscal
// MODE 1: col sweep        (stream x1, w = lv*p2 + lscal)      -> satr/wr
// MODE 2: P3(lev)+P1(lev+1) row sweep (w = lvA*p2+lwr, aux = lvB*p2+lsatr)
// MODE 3: final row sweep  (w = raw wr)                        -> cost -> out
template<int MODE>
__global__ void __launch_bounds__(TPB, 4)      // (B,minBlocks): VGPR<=64, no spill
emd_pass(float* __restrict__ ws, float* __restrict__ out,
         const float lvA, const float lvB)
{
    constexpr int SMEM = (MODE == 2) ? 40960 : 32768;   // 4 blocks/CU both ways
    __shared__ __align__(16) char smem[SMEM];
    float4* pts = reinterpret_cast<float4*>(smem);
    float*  aux = reinterpret_cast<float*>(smem + 32768);  // MODE 2 only
    float*  sc  = reinterpret_cast<float*>(smem);          // reduce overlay

    const int b    = blockIdx.x & 7;     // batch -> XCD pinning
    const int tile = blockIdx.x >> 3;    // 0..255
    const int t    = threadIdx.x;

    const float4* x1v = reinterpret_cast<const float4*>(WS_X1) + b * N_;
    const float4* x2v = reinterpret_cast<const float4*>(WS_X2) + b * N_;
    const float* lscal = WS_LSCAL + b * N_;
    const float* lsatr = WS_LSATR + b * N_;
    const float* lwr   = WS_LWR   + b * N_;
    const float* wrp   = WS_WR    + b * N_;

    // ---- staging ----
    for (int p = t; p < N_; p += TPB) {
        if (MODE == 0) {
            float4 v = x2v[p];
            pts[p] = make_float4(v.x, v.y, v.z, lvB * v.w);
        } else if (MODE == 1) {
            float4 v = x1v[p];
            pts[p] = make_float4(v.x, v.y, v.z, fmaf(lvB, v.w, lscal[p]));
        } else if (MODE == 2) {
            float4 v = x2v[p];
            pts[p] = make_float4(v.x, v.y, v.z, fmaf(lvA, v.w, lwr[p]));
            aux[p] = fmaf(lvB, v.w, lsatr[p]);
        } else {
            float4 v = x2v[p];
            pts[p] = make_float4(v.x, v.y, v.z, wrp[p]);
        }
    }

    // ---- owned coefficients (8 rows/cols, same for every thread) ----
    const float4* ownv = (MODE == 1) ? x2v : x1v;
    const int ob = tile * TILE;
    f2 kx[4], ky[4], kz[4], kc[4];
#pragma unroll
    for (int jp = 0; jp < 4; ++jp) {
        float4 v0 = ownv[ob + 2*jp], v1 = ownv[ob + 2*jp + 1];
        if (MODE == 0 || MODE == 1) {
            const float m2 = -2.f * lvB;
            kx[jp] = (f2){m2*v0.x, m2*v1.x};
            ky[jp] = (f2){m2*v0.y, m2*v1.y};
            kz[jp] = (f2){m2*v0.z, m2*v1.z};
            kc[jp] = (f2){lvB*v0.w, lvB*v1.w};
        } else if (MODE == 2) {
            kx[jp] = (f2){-2.f*v0.x, -2.f*v1.x};
            ky[jp] = (f2){-2.f*v0.y, -2.f*v1.y};
            kz[jp] = (f2){-2.f*v0.z, -2.f*v1.z};
            kc[jp] = (f2){v0.w, v1.w};
        } else {
            kx[jp] = (f2){v0.x, v1.x};
            ky[jp] = (f2){v0.y, v1.y};
            kz[jp] = (f2){v0.z, v1.z};
            kc[jp] = (f2){0.f, 0.f};
        }
    }
    __syncthreads();

    float s1[8], s2[8], s3[8];
    if (MODE == 0 || MODE == 1) sweep01(pts, kx, ky, kz, kc, t, s1);
    else if (MODE == 2) sweep2(pts, aux, kx, ky, kz, kc, lvA, lvB, t, s1, s2, s3);
    else                sweep3(pts, kx, ky, kz, t, s2);

    __syncthreads();   // pts dead -> overlay as reduce scratch

    if (MODE == 2) {
        wave_reduce8(s1, sc, 0, t);
        wave_reduce8(s2, sc, 1, t);
        wave_reduce8(s3, sc, 2, t);
    } else if (MODE == 3) {
        wave_reduce8(s2, sc, 0, t);
    } else {
        wave_reduce8(s1, sc, 0, t);
    }
    __syncthreads();

    const int gidx = b * N_ + tile * TILE + t;   // valid for t < 8

    if (t < 8) {
        float rs1 = 0.f, rs2 = 0.f, rs3 = 0.f;
#pragma unroll
        for (int w = 0; w < 8; ++w) rs1 += sc[w*16 + t];
        if (MODE == 2) {
#pragma unroll
            for (int w = 0; w < 8; ++w) rs2 += sc[128 + w*16 + t];
#pragma unroll
            for (int w = 0; w < 8; ++w) rs3 += sc[256 + w*16 + t];
        }
        if (MODE == 0) {
            const float scv = WS_SATL[gidx] / (rs1 + EPS_);
            WS_SCAL[gidx]  = scv;
            WS_LSCAL[gidx] = __log2f(scv);
        } else if (MODE == 1) {
            const float sr  = WS_SATR[gidx];
            const float w1s = sr * rs1;
            const float rr  = fminf(sr / (w1s + EPS_), 1.f);
            const float wrv = sr * rr;
            const float srn = fmaxf(sr - rr * w1s, 0.f);
            WS_SATR[gidx]  = srn;
            WS_WR[gidx]    = wrv;
            WS_LWR[gidx]   = __log2f(wrv);
            WS_LSATR[gidx] = __log2f(srn);
        } else if (MODE == 2) {
            const float scp = WS_SCAL[gidx];
            const float sln = fmaxf(WS_SATL[gidx] - scp * rs1, 0.f);
            WS_COST[gidx]   = fmaf(scp, rs2, WS_COST[gidx]);
            const float scn = sln / (rs3 + EPS_);
            WS_SATL[gidx]  = sln;
            WS_SCAL[gidx]  = scn;
            WS_LSCAL[gidx] = __log2f(scn);
        } else {
            float v = fmaf(WS_SCAL[gidx], rs1, WS_COST[gidx]);
            v += __shfl_xor(v, 1, 64);
            v += __shfl_xor(v, 2, 64);
            v += __shfl_xor(v, 4, 64);
            if (t == 0) atomicAdd(out + b, v);
        }
    }
}

extern "C" void kernel_launch(void* const* d_in, const int* in_sizes, int n_in,
                              void* d_out, int out_size, void* d_ws, size_t ws_size,
                              hipStream_t stream)
{
    const float* xyz1 = (const float*)d_in[0];
    const float* xyz2 = (const float*)d_in[1];
    float* out = (float*)d_out;
    float* ws  = (float*)d_ws;

    hipMemsetAsync(d_out, 0, B_ * sizeof(float), stream);
    emd_init<<<BN / 256, 256, 0, stream>>>(xyz1, xyz2, ws);

    static const float levels[11] = {
        -65536.f, -16384.f, -4096.f, -1024.f, -256.f,
        -64.f, -16.f, -4.f, -1.f, -0.25f, 0.f};

    emd_pass<0><<<NBLK, TPB, 0, stream>>>(ws, out, 0.f, levels[0] * LOG2E);
    emd_pass<1><<<NBLK, TPB, 0, stream>>>(ws, out, 0.f, levels[0] * LOG2E);
    for (int lev = 1; lev < 11; ++lev) {
        emd_pass<2><<<NBLK, TPB, 0, stream>>>(ws, out, levels[lev-1] * LOG2E,
                                                       levels[lev]   * LOG2E);
        emd_pass<1><<<NBLK, TPB, 0, stream>>>(ws, out, 0.f, levels[lev] * LOG2E);
    }
    emd_pass<3><<<NBLK, TPB, 0, stream>>>(ws, out, 0.f, 0.f);
}

// Round 14
// 471.507 us; speedup vs baseline: 1.9162x; 1.2017x over previous
//
#include <hip/hip_runtime.h>
#include <math.h>

typedef float f2 __attribute__((ext_vector_type(2)));

static constexpr int   B_   = 8;
static constexpr int   N_   = 2048;   // points per set
static constexpr int   TPB  = 1024;   // 16 waves/block
static constexpr int   TILE = 32;     // rows/cols owned per block
static constexpr int   NBLK = 512;    // 2 blocks/CU -> 32 waves/CU (max TLP)
static constexpr int   BN   = B_ * N_;
static constexpr float EPS_ = 1e-9f;
static constexpr float LOG2E = 1.4426950408889634f;

// ws layout (floats):
#define WS_X1    (ws)            // [4*BN] packed xyz1 (x,y,z,|p|^2)
#define WS_X2    (ws + 4*BN)     // [4*BN] packed xyz2
#define WS_SATL  (ws + 8*BN)
#define WS_SATR  (ws + 9*BN)
#define WS_SCAL  (ws + 10*BN)    // raw row scale
#define WS_LSCAL (ws + 11*BN)    // log2(scale)
#define WS_LSATR (ws + 12*BN)    // log2(satr)
#define WS_LWR   (ws + 13*BN)    // log2(wr)
#define WS_WR    (ws + 14*BN)    // raw wr
#define WS_COST  (ws + 15*BN)

__global__ void __launch_bounds__(256)
emd_init(const float* __restrict__ xyz1, const float* __restrict__ xyz2,
         float* __restrict__ ws)
{
    const int idx = blockIdx.x * 256 + threadIdx.x;
    if (idx >= BN) return;
    float x = xyz1[idx*3], y = xyz1[idx*3+1], z = xyz1[idx*3+2];
    reinterpret_cast<float4*>(WS_X1)[idx] =
        make_float4(x, y, z, fmaf(x,x, fmaf(y,y, z*z)));
    x = xyz2[idx*3]; y = xyz2[idx*3+1]; z = xyz2[idx*3+2];
    reinterpret_cast<float4*>(WS_X2)[idx] =
        make_float4(x, y, z, fmaf(x,x, fmaf(y,y, z*z)));
    WS_SATL[idx]  = 1.f;
    WS_SATR[idx]  = 1.f;
    WS_LSATR[idx] = 0.f;
    WS_COST[idx]  = 0.f;
}

// wave-level reduce: sum each of 8 row-partials over the 16 lanes of the
// wave sharing (t&3), then lanes 0..3 write [row][wave] into sc[a*512..].
__device__ __forceinline__ void wave_reduce8(float (&s)[8], float* sc, int a,
                                             int t)
{
#pragma unroll
    for (int j = 0; j < 8; ++j) {
        float v = s[j];
        v += __shfl_xor(v, 4, 64);
        v += __shfl_xor(v, 8, 64);
        v += __shfl_xor(v, 16, 64);
        v += __shfl_xor(v, 32, 64);
        s[j] = v;
    }
    const int lane = t & 63, w = t >> 6;       // 16 waves
    if (lane < 4) {
#pragma unroll
        for (int j = 0; j < 8; ++j)
            sc[a*512 + (lane*8 + j)*16 + w] = s[j];
    }
}

// ---- packed sweeps: l = t>>2, 8 iters, stride 256 ----
__device__ __forceinline__ void sweep01(const float4* pts,
    const f2 (&kx)[4], const f2 (&ky)[4], const f2 (&kz)[4], const f2 (&kc)[4],
    int t, float (&s1)[8])
{
#pragma unroll
    for (int j = 0; j < 8; ++j) s1[j] = 0.f;
    int l = t >> 2;
    float4 p = pts[l];
#pragma unroll 4
    for (int i = 0; i < 8; ++i) {
        const int ln = (l + 256) & (N_ - 1);
        const float4 pn = pts[ln];
        const f2 px = (f2){p.x,p.x}, py = (f2){p.y,p.y}, pz = (f2){p.z,p.z};
        const f2 pw = (f2){p.w,p.w};
#pragma unroll
        for (int jp = 0; jp < 4; ++jp) {
            f2 a = kc[jp] + pw;
            a = kz[jp] * pz + a;
            a = ky[jp] * py + a;
            a = kx[jp] * px + a;
            s1[2*jp]   += __builtin_amdgcn_exp2f(a.x);
            s1[2*jp+1] += __builtin_amdgcn_exp2f(a.y);
        }
        p = pn; l = ln;
    }
}

__device__ __forceinline__ void sweep2(const float4* pts, const float* auxB,
    const f2 (&kx)[4], const f2 (&ky)[4], const f2 (&kz)[4], const f2 (&kc)[4],
    float lvA, float lvB, int t, float (&s1)[8], float (&s2)[8], float (&s3)[8])
{
#pragma unroll
    for (int j = 0; j < 8; ++j) { s1[j] = 0.f; s2[j] = 0.f; s3[j] = 0.f; }
    int l = t >> 2;
    float4 p = pts[l];
    float  ab = auxB[l];
#pragma unroll 2
    for (int i = 0; i < 8; ++i) {
        const int ln = (l + 256) & (N_ - 1);
        const float4 pn = pts[ln];
        const float  abn = auxB[ln];
        const f2 px = (f2){p.x,p.x}, py = (f2){p.y,p.y}, pz = (f2){p.z,p.z};
        const float p2s = fmaf(p.x, p.x, fmaf(p.y, p.y, p.z * p.z));
#pragma unroll
        for (int jp = 0; jp < 4; ++jp) {
            f2 dq = kz[jp] * pz + kc[jp];
            dq = ky[jp] * py + dq;
            dq = kx[jp] * px + dq;                  // |q|^2 - 2 p.q
            const float sq0 = __builtin_amdgcn_sqrtf(fmaxf(dq.x + p2s, 0.f));
            const float sq1 = __builtin_amdgcn_sqrtf(fmaxf(dq.y + p2s, 0.f));
            const float eA0 = __builtin_amdgcn_exp2f(fmaf(lvA, dq.x, p.w));
            const float eA1 = __builtin_amdgcn_exp2f(fmaf(lvA, dq.y, p.w));
            const float eB0 = __builtin_amdgcn_exp2f(fmaf(lvB, dq.x, ab));
            const float eB1 = __builtin_amdgcn_exp2f(fmaf(lvB, dq.y, ab));
            s1[2*jp]   += eA0;            s1[2*jp+1] += eA1;
            s2[2*jp]    = fmaf(eA0, sq0, s2[2*jp]);
            s2[2*jp+1]  = fmaf(eA1, sq1, s2[2*jp+1]);
            s3[2*jp]   += eB0;            s3[2*jp+1] += eB1;
        }
        p = pn; ab = abn; l = ln;
    }
}

__device__ __forceinline__ void sweep3(const float4* pts,
    const f2 (&kx)[4], const f2 (&ky)[4], const f2 (&kz)[4],
    int t, float (&s2)[8])
{
#pragma unroll
    for (int j = 0; j < 8; ++j) s2[j] = 0.f;
    int l = t >> 2;
    float4 p = pts[l];
#pragma unroll 4
    for (int i = 0; i < 8; ++i) {
        const int ln = (l + 256) & (N_ - 1);
        const float4 pn = pts[ln];
#pragma unroll
        for (int jp = 0; jp < 4; ++jp) {
            const float dx0 = p.x - kx[jp].x, dy0 = p.y - ky[jp].x,
                        dz0 = p.z - kz[jp].x;
            const float dx1 = p.x - kx[jp].y, dy1 = p.y - ky[jp].y,
                        dz1 = p.z - kz[jp].y;
            const float d20 = fmaf(dx0,dx0, fmaf(dy0,dy0, dz0*dz0));
            const float d21 = fmaf(dx1,dx1, fmaf(dy1,dy1, dz1*dz1));
            s2[2*jp]   = fmaf(p.w, __builtin_amdgcn_sqrtf(fmaxf(d20,0.f)), s2[2*jp]);
            s2[2*jp+1] = fmaf(p.w, __builtin_amdgcn_sqrtf(fmaxf(d21,0.f)), s2[2*jp+1]);
        }
        p = pn; l = ln;
    }
}

// MODE 0: first row sweep  (stream x2, w = lv*p2 + lsatr(=0))  -> scal/lscal
// MODE 1: col sweep        (stream x1, w = lv*p2 + lscal)      -> satr/wr
// MODE 2: P3(lev)+P1(lev+1) row sweep (w = lvA*p2+lwr, aux = lvB*p2+lsatr)
// MODE 3: final row sweep  (w = raw wr)                        -> cost -> out
template<int MODE>
__global__ void __launch_bounds__(TPB, 2)   // 2 blocks/CU: VGPR cap 64 (no spill)
emd_pass(float* __restrict__ ws, float* __restrict__ out,
         const float lvA, const float lvB)
{
    __shared__ __align__(16) float4 pts[N_];   // 32 KB
    __shared__ float aux[N_];                  // 8 KB: staged arg / reduce scratch

    const int b    = blockIdx.x & 7;     // batch -> XCD pinning
    const int tile = blockIdx.x >> 3;
    const int t    = threadIdx.x;
    const int rg   = t & 3;

    const float4* x1v = reinterpret_cast<const float4*>(WS_X1) + b * N_;
    const float4* x2v = reinterpret_cast<const float4*>(WS_X2) + b * N_;
    const float* lscal = WS_LSCAL + b * N_;
    const float* lsatr = WS_LSATR + b * N_;
    const float* lwr   = WS_LWR   + b * N_;
    const float* wrp   = WS_WR    + b * N_;

    // ---- staging ----
    for (int p = t; p < N_; p += TPB) {
        if (MODE == 0) {
            float4 v = x2v[p];
            pts[p] = make_float4(v.x, v.y, v.z, lvB * v.w);
        } else if (MODE == 1) {
            float4 v = x1v[p];
            pts[p] = make_float4(v.x, v.y, v.z, fmaf(lvB, v.w, lscal[p]));
        } else if (MODE == 2) {
            float4 v = x2v[p];
            pts[p] = make_float4(v.x, v.y, v.z, fmaf(lvA, v.w, lwr[p]));
            aux[p] = fmaf(lvB, v.w, lsatr[p]);
        } else {
            float4 v = x2v[p];
            pts[p] = make_float4(v.x, v.y, v.z, wrp[p]);
        }
    }

    // ---- owned coefficients, pair-packed ----
    const float4* ownv = (MODE == 1) ? x2v : x1v;
    const int ob = tile * TILE + rg * 8;
    f2 kx[4], ky[4], kz[4], kc[4];
#pragma unroll
    for (int jp = 0; jp < 4; ++jp) {
        float4 v0 = ownv[ob + 2*jp], v1 = ownv[ob + 2*jp + 1];
        if (MODE == 0 || MODE == 1) {
            const float m2 = -2.f * lvB;
            kx[jp] = (f2){m2*v0.x, m2*v1.x};
            ky[jp] = (f2){m2*v0.y, m2*v1.y};
            kz[jp] = (f2){m2*v0.z, m2*v1.z};
            kc[jp] = (f2){lvB*v0.w, lvB*v1.w};
        } else if (MODE == 2) {
            kx[jp] = (f2){-2.f*v0.x, -2.f*v1.x};
            ky[jp] = (f2){-2.f*v0.y, -2.f*v1.y};
            kz[jp] = (f2){-2.f*v0.z, -2.f*v1.z};
            kc[jp] = (f2){v0.w, v1.w};
        } else {
            kx[jp] = (f2){v0.x, v1.x};
            ky[jp] = (f2){v0.y, v1.y};
            kz[jp] = (f2){v0.z, v1.z};
            kc[jp] = (f2){0.f, 0.f};
        }
    }
    __syncthreads();

    float s1[8], s2[8], s3[8];
    if (MODE == 0 || MODE == 1) sweep01(pts, kx, ky, kz, kc, t, s1);
    else if (MODE == 2) sweep2(pts, aux, kx, ky, kz, kc, lvA, lvB, t, s1, s2, s3);
    else                sweep3(pts, kx, ky, kz, t, s2);

    __syncthreads();   // staged aux dead -> reuse as reduce scratch

    if (MODE == 2) {
        wave_reduce8(s1, aux, 0, t);
        wave_reduce8(s2, aux, 1, t);
        wave_reduce8(s3, aux, 2, t);
    } else if (MODE == 3) {
        wave_reduce8(s2, aux, 0, t);
    } else {
        wave_reduce8(s1, aux, 0, t);
    }
    __syncthreads();

    const int gidx = b * N_ + tile * TILE + t;   // valid for t < 32

    if (t < 32) {
        float rs1 = 0.f, rs2 = 0.f, rs3 = 0.f;
#pragma unroll
        for (int w = 0; w < 16; ++w) rs1 += aux[t*16 + w];
        if (MODE == 2) {
#pragma unroll
            for (int w = 0; w < 16; ++w) rs2 += aux[512 + t*16 + w];
#pragma unroll
            for (int w = 0; w < 16; ++w) rs3 += aux[1024 + t*16 + w];
        }
        if (MODE == 0) {
            const float scv = WS_SATL[gidx] / (rs1 + EPS_);
            WS_SCAL[gidx]  = scv;
            WS_LSCAL[gidx] = __log2f(scv);
        } else if (MODE == 1) {
            const float sr  = WS_SATR[gidx];
            const float w1s = sr * rs1;
            const float rr  = fminf(sr / (w1s + EPS_), 1.f);
            const float wrv = sr * rr;
            const float srn = fmaxf(sr - rr * w1s, 0.f);
            WS_SATR[gidx]  = srn;
            WS_WR[gidx]    = wrv;
            WS_LWR[gidx]   = __log2f(wrv);
            WS_LSATR[gidx] = __log2f(srn);
        } else if (MODE == 2) {
            const float scp = WS_SCAL[gidx];
            const float sln = fmaxf(WS_SATL[gidx] - scp * rs1, 0.f);
            WS_COST[gidx]   = fmaf(scp, rs2, WS_COST[gidx]);
            const float scn = sln / (rs3 + EPS_);
            WS_SATL[gidx]  = sln;
            WS_SCAL[gidx]  = scn;
            WS_LSCAL[gidx] = __log2f(scn);
        } else {
            float v = fmaf(WS_SCAL[gidx], rs1, WS_COST[gidx]);
#pragma unroll
            for (int k = 16; k >= 1; k >>= 1) v += __shfl_xor(v, k, 32);
            if (t == 0) atomicAdd(out + b, v);
        }
    }
}

extern "C" void kernel_launch(void* const* d_in, const int* in_sizes, int n_in,
                              void* d_out, int out_size, void* d_ws, size_t ws_size,
                              hipStream_t stream)
{
    const float* xyz1 = (const float*)d_in[0];
    const float* xyz2 = (const float*)d_in[1];
    float* out = (float*)d_out;
    float* ws  = (float*)d_ws;

    hipMemsetAsync(d_out, 0, B_ * sizeof(float), stream);
    emd_init<<<BN / 256, 256, 0, stream>>>(xyz1, xyz2, ws);

    static const float levels[11] = {
        -65536.f, -16384.f, -4096.f, -1024.f, -256.f,
        -64.f, -16.f, -4.f, -1.f, -0.25f, 0.f};

    emd_pass<0><<<NBLK, TPB, 0, stream>>>(ws, out, 0.f, levels[0] * LOG2E);
    emd_pass<1><<<NBLK, TPB, 0, stream>>>(ws, out, 0.f, levels[0] * LOG2E);
    for (int lev = 1; lev < 11; ++lev) {
        emd_pass<2><<<NBLK, TPB, 0, stream>>>(ws, out, levels[lev-1] * LOG2E,
                                                       levels[lev]   * LOG2E);
        emd_pass<1><<<NBLK, TPB, 0, stream>>>(ws, out, 0.f, levels[lev] * LOG2E);
    }
    emd_pass<3><<<NBLK, TPB, 0, stream>>>(ws, out, 0.f, 0.f);
}

// Round 15
// 321.194 us; speedup vs baseline: 2.8129x; 1.4680x over previous
//
#include <hip/hip_runtime.h>
#include <math.h>

typedef float f2 __attribute__((ext_vector_type(2)));

static constexpr int   B_   = 8;
static constexpr int   N_   = 2048;   // points per set
static constexpr int   TPB  = 256;
static constexpr int   TILE = 16;     // rows/cols owned per block
static constexpr int   BPB  = 128;    // blocks per batch
static constexpr int   NBLK = B_ * BPB;   // 1024 blocks = 4/CU exactly
static constexpr int   BN   = B_ * N_;
static constexpr float EPS_ = 1e-9f;
static constexpr float LOG2E = 1.4426950408889634f;

// ws layout (floats):
#define WS_X1    (ws)            // [4*BN] packed xyz1 (x,y,z,|p|^2)
#define WS_X2    (ws + 4*BN)     // [4*BN] packed xyz2
#define WS_SATL  (ws + 8*BN)
#define WS_SATR  (ws + 9*BN)
#define WS_SCAL  (ws + 10*BN)    // raw row scale
#define WS_LSCAL (ws + 11*BN)    // log2(scale)
#define WS_LSATR (ws + 12*BN)    // log2(satr)
#define WS_LWR   (ws + 13*BN)    // log2(wr)
#define WS_WR    (ws + 14*BN)    // raw wr
#define WS_COST  (ws + 15*BN)

__global__ void __launch_bounds__(TPB)
emd_init(const float* __restrict__ xyz1, const float* __restrict__ xyz2,
         float* __restrict__ ws)
{
    const int idx = blockIdx.x * TPB + threadIdx.x;
    if (idx >= BN) return;
    float x = xyz1[idx*3], y = xyz1[idx*3+1], z = xyz1[idx*3+2];
    reinterpret_cast<float4*>(WS_X1)[idx] =
        make_float4(x, y, z, fmaf(x,x, fmaf(y,y, z*z)));
    x = xyz2[idx*3]; y = xyz2[idx*3+1]; z = xyz2[idx*3+2];
    reinterpret_cast<float4*>(WS_X2)[idx] =
        make_float4(x, y, z, fmaf(x,x, fmaf(y,y, z*z)));
    WS_SATL[idx]  = 1.f;
    WS_SATR[idx]  = 1.f;
    WS_LSATR[idx] = 0.f;
    WS_COST[idx]  = 0.f;
}

// fused reduction of NA arrays of 8 row-partials; rs[a] valid for t < 16.
// sc = 32KB scratch (overlays pts; leading sync covers last reader).
template<int NA>
__device__ __forceinline__ void reduce_multi(float* sc, const float (*s)[8],
                                             int t, float* rs)
{
    const int c = t >> 1, g = t & 1;
    __syncthreads();
#pragma unroll
    for (int a = 0; a < NA; ++a) {
        float* red = sc + a * 2176;     // [128][17]
#pragma unroll
        for (int j = 0; j < 8; ++j) red[c*17 + g*8 + j] = s[a][j];
    }
    __syncthreads();
    {
        const int col = t & 15, seg = t >> 4;
#pragma unroll
        for (int a = 0; a < NA; ++a) {
            const float* red = sc + a * 2176;
            float v = 0.f;
#pragma unroll
            for (int k = 0; k < 8; ++k) v += red[(seg*8 + k)*17 + col];
            sc[6528 + a*272 + seg*17 + col] = v;     // [16][17] per array
        }
    }
    __syncthreads();
    if (t < 16) {
#pragma unroll
        for (int a = 0; a < NA; ++a) {
            float r = 0.f;
#pragma unroll
            for (int q = 0; q < 16; ++q) r += sc[6528 + a*272 + q*17 + t];
            rs[a] = r;
        }
    }
}

// MODE 0: first row sweep  (stream x2, w = lv*p2 + lsatr(=0))  -> scal/lscal
// MODE 1: col sweep        (stream x1, w = lv*p2 + lscal)      -> satr/wr
// MODE 2: P3(lev)+P1(lev+1) row sweep (w = lvA*p2+lwr, aux = lvB*p2+lsatr)
// MODE 3: final row sweep  (w = raw wr)                        -> cost -> out
template<int MODE>
__global__ void __launch_bounds__(TPB, 4)
emd_pass(float* __restrict__ ws, float* __restrict__ out,
         const float lvA, const float lvB)
{
    constexpr int SMEM = (MODE == 2) ? 40960 : 32768;
    __shared__ __align__(16) char smem[SMEM];
    float4* pts  = reinterpret_cast<float4*>(smem);
    float*  auxB = reinterpret_cast<float*>(smem + 32768);  // MODE 2 only
    float*  sc   = reinterpret_cast<float*>(smem);          // reduce overlay

    const int b    = blockIdx.x >> 7;
    const int tile = blockIdx.x & 127;
    const int t    = threadIdx.x;

    const float4* x1v = reinterpret_cast<const float4*>(WS_X1) + b * N_;
    const float4* x2v = reinterpret_cast<const float4*>(WS_X2) + b * N_;
    const float* lscal = WS_LSCAL + b * N_;
    const float* lsatr = WS_LSATR + b * N_;
    const float* lwr   = WS_LWR   + b * N_;
    const float* wrp   = WS_WR    + b * N_;

    // ---- staging ----
    for (int p = t; p < N_; p += TPB) {
        if (MODE == 0) {
            float4 v = x2v[p];
            pts[p] = make_float4(v.x, v.y, v.z, lvB * v.w);
        } else if (MODE == 1) {
            float4 v = x1v[p];
            pts[p] = make_float4(v.x, v.y, v.z, fmaf(lvB, v.w, lscal[p]));
        } else if (MODE == 2) {
            float4 v = x2v[p];
            pts[p]  = make_float4(v.x, v.y, v.z, fmaf(lvA, v.w, lwr[p]));
            auxB[p] = fmaf(lvB, v.w, lsatr[p]);
        } else {
            float4 v = x2v[p];
            pts[p] = make_float4(v.x, v.y, v.z, wrp[p]);
        }
    }

    // ---- owned coefficients, packed in row pairs ----
    const float4* ownv = (MODE == 1) ? x2v : x1v;
    const int ob = tile * TILE + (t & 1) * 8;
    f2 kx[4], ky[4], kz[4], kc[4];
#pragma unroll
    for (int jp = 0; jp < 4; ++jp) {
        float4 v0 = ownv[ob + 2*jp], v1 = ownv[ob + 2*jp + 1];
        if (MODE == 0 || MODE == 1) {
            const float m2 = -2.f * lvB;
            kx[jp] = (f2){m2*v0.x, m2*v1.x};
            ky[jp] = (f2){m2*v0.y, m2*v1.y};
            kz[jp] = (f2){m2*v0.z, m2*v1.z};
            kc[jp] = (f2){lvB*v0.w, lvB*v1.w};
        } else {
            kx[jp] = (f2){-2.f*v0.x, -2.f*v1.x};
            ky[jp] = (f2){-2.f*v0.y, -2.f*v1.y};
            kz[jp] = (f2){-2.f*v0.z, -2.f*v1.z};
            kc[jp] = (f2){v0.w, v1.w};
        }
    }
    __syncthreads();

    // ---- sweep: 16 iters, 2-deep prefetch, packed dot products ----
    float s1[8], s2[8], s3[8];
#pragma unroll
    for (int j = 0; j < 8; ++j) { s1[j] = 0.f; s2[j] = 0.f; s3[j] = 0.f; }

    int l = t >> 1;
    float4 p = pts[l];
    float  ab = (MODE == 2) ? auxB[l] : 0.f;

#pragma unroll 2
    for (int i = 0; i < 16; ++i) {
        const int ln = (l + 128) & (N_ - 1);
        const float4 pn = pts[ln];
        float abn = 0.f;
        if (MODE == 2) abn = auxB[ln];

        const f2 px = (f2){p.x, p.x}, py = (f2){p.y, p.y}, pz = (f2){p.z, p.z};
        float p2s = 0.f;
        if (MODE == 2 || MODE == 3)
            p2s = fmaf(p.x, p.x, fmaf(p.y, p.y, p.z * p.z));

#pragma unroll
        for (int jp = 0; jp < 4; ++jp) {
            if (MODE == 0 || MODE == 1) {
                f2 a = kc[jp] + (f2){p.w, p.w};
                a = kz[jp] * pz + a;
                a = ky[jp] * py + a;
                a = kx[jp] * px + a;
                s1[2*jp]   += __builtin_amdgcn_exp2f(a.x);
                s1[2*jp+1] += __builtin_amdgcn_exp2f(a.y);
            } else if (MODE == 2) {
                f2 dq = kz[jp] * pz + kc[jp];
                dq = ky[jp] * py + dq;
                dq = kx[jp] * px + dq;                  // |q|^2 - 2 p.q
                const float d20 = dq.x + p2s, d21 = dq.y + p2s;
                const float sq0 = __builtin_amdgcn_sqrtf(fmaxf(d20, 0.f));
                const float sq1 = __builtin_amdgcn_sqrtf(fmaxf(d21, 0.f));
                const float eA0 = __builtin_amdgcn_exp2f(fmaf(lvA, dq.x, p.w));
                const float eA1 = __builtin_amdgcn_exp2f(fmaf(lvA, dq.y, p.w));
                const float eB0 = __builtin_amdgcn_exp2f(fmaf(lvB, dq.x, ab));
                const float eB1 = __builtin_amdgcn_exp2f(fmaf(lvB, dq.y, ab));
                s1[2*jp]   += eA0;            s1[2*jp+1] += eA1;
                s2[2*jp]    = fmaf(eA0, sq0, s2[2*jp]);
                s2[2*jp+1]  = fmaf(eA1, sq1, s2[2*jp+1]);
                s3[2*jp]   += eB0;            s3[2*jp+1] += eB1;
            } else {
                f2 dq = kz[jp] * pz + kc[jp];
                dq = ky[jp] * py + dq;
                dq = kx[jp] * px + dq;
                const float sq0 = __builtin_amdgcn_sqrtf(fmaxf(dq.x + p2s, 0.f));
                const float sq1 = __builtin_amdgcn_sqrtf(fmaxf(dq.y + p2s, 0.f));
                s2[2*jp]   = fmaf(p.w, sq0, s2[2*jp]);
                s2[2*jp+1] = fmaf(p.w, sq1, s2[2*jp+1]);
            }
        }
        p = pn; ab = abn; l = ln;
    }

    // ---- reductions + epilogue ----
    const int gidx = b * N_ + tile * TILE + t;   // valid for t < 16

    if (MODE == 0) {
        float rs[1];
        reduce_multi<1>(sc, &s1, t, rs);
        if (t < TILE) {
            const float scv = WS_SATL[gidx] / (rs[0] + EPS_);
            WS_SCAL[gidx]  = scv;
            WS_LSCAL[gidx] = __log2f(scv);
        }
    } else if (MODE == 1) {
        float rs[1];
        reduce_multi<1>(sc, &s1, t, rs);
        if (t < TILE) {
            const float sr  = WS_SATR[gidx];
            const float w1s = sr * rs[0];
            const float rr  = fminf(sr / (w1s + EPS_), 1.f);
            const float wrv = sr * rr;
            const float srn = fmaxf(sr - rr * w1s, 0.f);
            WS_SATR[gidx]  = srn;
            WS_WR[gidx]    = wrv;
            WS_LWR[gidx]   = __log2f(wrv);
            WS_LSATR[gidx] = __log2f(srn);
        }
    } else if (MODE == 2) {
        float sall[3][8];
#pragma unroll
        for (int j = 0; j < 8; ++j) {
            sall[0][j] = s1[j]; sall[1][j] = s2[j]; sall[2][j] = s3[j];
        }
        float rs[3];
        reduce_multi<3>(sc, sall, t, rs);
        if (t < TILE) {
            const float scp = WS_SCAL[gidx];
            const float sln = fmaxf(WS_SATL[gidx] - scp * rs[0], 0.f);
            WS_COST[gidx]   = fmaf(scp, rs[1], WS_COST[gidx]);
            const float scn = sln / (rs[2] + EPS_);
            WS_SATL[gidx]  = sln;
            WS_SCAL[gidx]  = scn;
            WS_LSCAL[gidx] = __log2f(scn);
        }
    } else {
        float rs[1];
        reduce_multi<1>(sc, &s2, t, rs);
        if (t < 16) {
            float v = fmaf(WS_SCAL[gidx], rs[0], WS_COST[gidx]);
#pragma unroll
            for (int k = 8; k >= 1; k >>= 1) v += __shfl_xor(v, k, 16);
            if (t == 0) atomicAdd(out + b, v);
        }
    }
}

extern "C" void kernel_launch(void* const* d_in, const int* in_sizes, int n_in,
                              void* d_out, int out_size, void* d_ws, size_t ws_size,
                              hipStream_t stream)
{
    const float* xyz1 = (const float*)d_in[0];
    const float* xyz2 = (const float*)d_in[1];
    float* out = (float*)d_out;
    float* ws  = (float*)d_ws;

    hipMemsetAsync(d_out, 0, B_ * sizeof(float), stream);
    emd_init<<<BN / TPB, TPB, 0, stream>>>(xyz1, xyz2, ws);

    static const float levels[11] = {
        -65536.f, -16384.f, -4096.f, -1024.f, -256.f,
        -64.f, -16.f, -4.f, -1.f, -0.25f, 0.f};

    emd_pass<0><<<NBLK, TPB, 0, stream>>>(ws, out, 0.f, levels[0] * LOG2E);
    emd_pass<1><<<NBLK, TPB, 0, stream>>>(ws, out, 0.f, levels[0] * LOG2E);
    for (int lev = 1; lev < 11; ++lev) {
        emd_pass<2><<<NBLK, TPB, 0, stream>>>(ws, out, levels[lev-1] * LOG2E,
                                                       levels[lev]   * LOG2E);
        emd_pass<1><<<NBLK, TPB, 0, stream>>>(ws, out, 0.f, levels[lev] * LOG2E);
    }
    emd_pass<3><<<NBLK, TPB, 0, stream>>>(ws, out, 0.f, 0.f);
}